// Round 1
// baseline (311.228 us; speedup 1.0000x reference)
//
#include <hip/hip_runtime.h>
#include <math.h>

// Problem geometry
#define W_ 512
#define H_ 512
#define HW_ 262144          // 512*512 = 2^18
#define HW4_ 65536          // HW/4 (float4 units)
#define CHW_ 786432         // 3*HW

// d_out offsets (floats), return order:
// (Bn, tn, Jn, G, Hn, Pn, Qn, un, vn, Xn, Yn, gamma_3)
#define O_Bn 0
#define O_tn 3145728
#define O_Jn 6291456
#define O_G  9437184
#define O_Hn 12582912
#define O_Pn 15728640
#define O_Qn 16777216
#define O_un 17825792
#define O_vn 20971520
#define O_Xn 24117248
#define O_Yn 27262976
#define O_g3 30408704

#define LAM2 0.7f
#define LAM3 0.3f

// ws layout (floats)
#define WS_ACC 0                      // 64 floats, zeroed by hipMemsetAsync
#define WS_A   16384                  // conv input A: 4b x 3c x HW = 3145728 floats
#define WS_SCR (16384 + 3145728)      // h-min scratch: 2*4*HW floats

// native clang vector for nontemporal 16B stores
typedef float nfloat4 __attribute__((ext_vector_type(4)));

__device__ __forceinline__ void nt_store4(float4 v, float4* p) {
    nfloat4 nv; nv.x = v.x; nv.y = v.y; nv.z = v.z; nv.w = v.w;
    __builtin_nontemporal_store(nv, (nfloat4*)p);
}

// ---- Pass A: fused reduction over I, t, B_p, J -> 60 atomic accumulators.
// Per batch b, 15 sums: sJ[c] (3), S1[c] (3), S2[l][c] (9).
__global__ __launch_bounds__(256) void kRed(const float* __restrict__ J,
                                            const float* __restrict__ tt,
                                            const float* __restrict__ B_p,
                                            const float* __restrict__ I,
                                            float* __restrict__ acc) {
    int blk = blockIdx.x;              // 0..511
    int b = blk >> 7, chunk = blk & 127;
    size_t pb = (size_t)b * (CHW_ / 4);
    size_t cb = (size_t)chunk * 512;
    const float4* J4 = (const float4*)J;
    const float4* t4 = (const float4*)tt;
    const float4* B4 = (const float4*)B_p;
    const float4* I4 = (const float4*)I;

    float aJ[3] = {0.f, 0.f, 0.f};
    float a1[3] = {0.f, 0.f, 0.f};
    float a2[9] = {0.f, 0.f, 0.f, 0.f, 0.f, 0.f, 0.f, 0.f, 0.f};

    #pragma unroll
    for (int k = 0; k < 2; ++k) {
        size_t o = cb + threadIdx.x + k * 256;
        float4 j0 = J4[pb + 0 * HW4_ + o];
        float4 j1 = J4[pb + 1 * HW4_ + o];
        float4 j2 = J4[pb + 2 * HW4_ + o];
        #pragma unroll
        for (int c = 0; c < 3; ++c) {
            float4 tv = t4[pb + (size_t)c * HW4_ + o];
            float4 bp = B4[pb + (size_t)c * HW4_ + o];
            float4 iv = I4[pb + (size_t)c * HW4_ + o];
            float4 jc = (c == 0) ? j0 : (c == 1 ? j1 : j2);
#define REDC(m) { \
            float omt = 1.f - tv.m; \
            float r = 1.f / (omt * omt + LAM3); \
            float g = tv.m * omt * r; \
            aJ[c] += jc.m; \
            a1[c] += (LAM3 * bp.m - (jc.m * tv.m - iv.m) * omt) * r; \
            a2[0 * 3 + c] += j0.m * g; \
            a2[1 * 3 + c] += j1.m * g; \
            a2[2 * 3 + c] += j2.m * g; }
            REDC(x) REDC(y) REDC(z) REDC(w)
#undef REDC
        }
    }

    float vals[15];
    #pragma unroll
    for (int c = 0; c < 3; ++c) { vals[c] = aJ[c]; vals[3 + c] = a1[c]; }
    #pragma unroll
    for (int s = 0; s < 9; ++s) vals[6 + s] = a2[s];

    __shared__ float lds[4][15];
    int lane = threadIdx.x & 63, w = threadIdx.x >> 6;
    #pragma unroll
    for (int s = 0; s < 15; ++s) {
        float v = vals[s];
        #pragma unroll
        for (int off = 32; off; off >>= 1) v += __shfl_down(v, off, 64);
        if (lane == 0) lds[w][s] = v;
    }
    __syncthreads();
    if (threadIdx.x < 15) {
        int s = threadIdx.x;
        atomicAdd(&acc[b * 15 + s],
                  (lds[0][s] + lds[1][s]) + (lds[2][s] + lds[3][s]));
    }
}

// ---- Pass B: fused elementwise + finalize-prologue + horizontal 35-tap
// reflect-min. Conv input A = tn + X/g4 written to ws (conv moved to kTail —
// no more halo-row recompute, LDS 35KB -> 9KB). Block = 2 rows.
__global__ __launch_bounds__(256) void kMain(
    const float* __restrict__ I, const float* __restrict__ t_p,
    const float* __restrict__ Hm, const float* __restrict__ Xm,
    const float* __restrict__ J, const float* __restrict__ u,
    const float* __restrict__ v, const float* __restrict__ Y,
    const float* __restrict__ G,
    const float* __restrict__ g1p, const float* __restrict__ g2p,
    const float* __restrict__ g3p, const float* __restrict__ g4p,
    const float* __restrict__ g5p, const float* __restrict__ t1w,
    const float* __restrict__ acc,
    float* __restrict__ out, float* __restrict__ wsA, float* __restrict__ scr)
{
    __shared__ float pad[2][2][560];    // h-min rows, main data at [17,529)
    __shared__ float sAlpha[3], sBnS[3];
    __shared__ int sI2;

    int t = threadIdx.x;
    int b = blockIdx.x >> 8;            // 4 batches x 256 row-pairs
    int y0b = (blockIdx.x & 255) * 2;
    float g1 = g1p[0], g2 = g2p[0], g3 = g3p[0], g4 = g4p[0], g5 = g5p[0];
    float ig4 = 1.f / g4;

    // ---- prologue: per-block finalize (argsort, alpha, BnS) ----
    if (t == 0) {
        const float invHW = 1.0f / (float)HW_;
        float tot[15];
        #pragma unroll
        for (int s = 0; s < 15; ++s) tot[s] = acc[b * 15 + s];
        float m[3] = {tot[0] * invHW, tot[1] * invHW, tot[2] * invHW};
        int r[3];
        #pragma unroll
        for (int i = 0; i < 3; ++i) {
            int ri = 0;
            #pragma unroll
            for (int j = 0; j < 3; ++j)
                if (j != i && (m[j] < m[i] || (m[j] == m[i] && j < i))) ri++;
            r[i] = ri;   // ascending stable rank
        }
        int idx[3]; float ms[3];
        #pragma unroll
        for (int i = 0; i < 3; ++i) { idx[r[i]] = i; ms[r[i]] = m[i]; }
        sI2 = idx[2];
        float a[3] = {0.f, 0.f, 0.f};
        a[idx[1]] = ms[2] - ms[1];
        a[idx[0]] = ms[2] - ms[0];
        #pragma unroll
        for (int c = 0; c < 3; ++c) {
            sAlpha[c] = a[c];
            sBnS[c] = (tot[3 + c] - a[c] * tot[6 + idx[2] * 3 + c]) * invHW;
        }
        if (blockIdx.x == 0) out[O_g3] = g3;
    }
    __syncthreads();

    int rrow = t >> 7;                  // row within block: 0..1
    int xq = t & 127;                   // float4 col
    int x0 = xq * 4;
    size_t pb = (size_t)b * (CHW_ / 4);
    size_t q = (size_t)(y0b + rrow) * 128 + xq;   // float4 offset in plane
    float wc[3] = {t1w[0], t1w[1], t1w[2]};
    int i2 = sI2;
    const float4* I4p = (const float4*)I;
    const float4* tp4p = (const float4*)t_p;
    const float4* H4p = (const float4*)Hm;
    const float4* X4p = (const float4*)Xm;
    const float4* J4p = (const float4*)J;
    const float4* u4p = (const float4*)u;
    const float4* v4p = (const float4*)v;
    const float4* Y4p = (const float4*)Y;
    const float4* G4p = (const float4*)G;
    float4* o4 = (float4*)out;
    float4* wsA4 = (float4*)wsA;

    // ---- phase 1: main 2 rows, full elementwise ----
    float4 j0 = J4p[pb + 0 * HW4_ + q];
    float4 j1 = J4p[pb + 1 * HW4_ + q];
    float4 j2 = J4p[pb + 2 * HW4_ + q];
    float4 Jl = (i2 == 0) ? j0 : (i2 == 1 ? j1 : j2);   // wave-uniform select
    float4 t1 = make_float4(0.f, 0.f, 0.f, 0.f);
    float4 Isv[3], Xsv[3]; float Bsv[3];
    const float den2 = LAM2 + g4;
    #pragma unroll
    for (int c = 0; c < 3; ++c) {
        size_t o = pb + (size_t)c * HW4_ + q;
        float4 I4 = I4p[o], tp4 = tp4p[o], H4 = H4p[o], X4 = X4p[o];
        float4 Jv = (c == 0) ? j0 : (c == 1 ? j1 : j2);
        float al = sAlpha[c], Bnv = sBnS[c];
        float wcc = wc[c];
#define STEP1(m) { \
        float d_ = (Jv.m + al * Jl.m) - Bnv; \
        float tnr_ = (LAM2 * tp4.m + g4 * H4.m - (Bnv - I4.m) * d_ - X4.m) / (d_ * d_ + den2); \
        t1.m += wcc * tnr_; }
        STEP1(x) STEP1(y) STEP1(z) STEP1(w)
#undef STEP1
        Isv[c] = I4; Xsv[c] = X4; Bsv[c] = Bnv;
    }
    float g345 = g3 + g4 + g5;
    float4 invDen;
    invDen.x = 1.f / (t1.x * t1.x + g345);
    invDen.y = 1.f / (t1.y * t1.y + g345);
    invDen.z = 1.f / (t1.z * t1.z + g345);
    invDen.w = 1.f / (t1.w * t1.w + g345);
    float invDu = 1.f / (g1 + g4), invDv = 1.f / (g2 + g5);
    float4 cu = make_float4(1e30f, 1e30f, 1e30f, 1e30f);
    float4 cv = cu;
    #pragma unroll
    for (int c = 0; c < 3; ++c) {
        size_t o = pb + (size_t)c * HW4_ + q;
        float4 u4 = u4p[o], v4 = v4p[o], Y4 = Y4p[o], G4 = G4p[o];
        float Bnv = Bsv[c];
        float4 Jn4, un4, vn4, Yn4;
#define STEP2(m) { \
        float Jn_ = (t1.m * (Isv[c].m - Bnv * (1.f - t1.m)) + g3 * G4.m + g4 * u4.m \
                     - g5 * v4.m - Y4.m + g5) * invDen.m; \
        float un_ = (g1 * u4.m + g4 * Jn_) * invDu; \
        float vn_ = (g2 * v4.m - g5 * Jn_ + g5) * invDv; \
        Jn4.m = Jn_; un4.m = un_; vn4.m = vn_; \
        Yn4.m = Y4.m + g3 * (Jn_ - G4.m); \
        cu.m = fminf(cu.m, un_); cv.m = fminf(cv.m, vn_); }
        STEP2(x) STEP2(y) STEP2(z) STEP2(w)
#undef STEP2
        nt_store4(make_float4(Bnv, Bnv, Bnv, Bnv), &o4[O_Bn / 4 + o]);
        nt_store4(t1,  &o4[O_tn / 4 + o]);
        nt_store4(Jn4, &o4[O_Jn / 4 + o]);
        nt_store4(G4,  &o4[O_G  / 4 + o]);
        nt_store4(un4, &o4[O_un / 4 + o]);
        nt_store4(vn4, &o4[O_vn / 4 + o]);
        nt_store4(Yn4, &o4[O_Yn / 4 + o]);
        // conv input A -> ws (regular store: re-read by kTail, keep cacheable)
        float4 A4;
        A4.x = t1.x + Xsv[c].x * ig4; A4.y = t1.y + Xsv[c].y * ig4;
        A4.z = t1.z + Xsv[c].z * ig4; A4.w = t1.w + Xsv[c].w * ig4;
        wsA4[(size_t)(b * 3 + c) * HW4_ + q] = A4;
    }
    // h-min staging
    pad[0][rrow][17 + x0 + 0] = cu.x;
    pad[0][rrow][17 + x0 + 1] = cu.y;
    pad[0][rrow][17 + x0 + 2] = cu.z;
    pad[0][rrow][17 + x0 + 3] = cu.w;
    pad[1][rrow][17 + x0 + 0] = cv.x;
    pad[1][rrow][17 + x0 + 1] = cv.y;
    pad[1][rrow][17 + x0 + 2] = cv.z;
    pad[1][rrow][17 + x0 + 3] = cv.w;
    __syncthreads();

    // ---- pad reflect edge fill ----
    if (t < 136) {                      // 4 rows x 34 cells
        int which = t / 34, e = t % 34;
        int tens = which >> 1, rw = which & 1;
        int j   = (e < 17) ? e : (529 + (e - 17));
        int src = (e < 17) ? (34 - j) : (1056 - j);
        pad[tens][rw][j] = pad[tens][rw][src];
    }
    __syncthreads();

    // ---- phase 2: horizontal 35-tap reflect min -> scr ----
    int yg = y0b + rrow;
    #pragma unroll
    for (int tens = 0; tens < 2; ++tens) {
        const float* rowp = &pad[tens][rrow][0];
        const float4* rp4 = (const float4*)(rowp + x0);   // 16B-aligned
        float4 qv = rp4[0];
        float a0 = qv.x, a1 = qv.y, a2 = qv.z;
        float mc = qv.w;
        #pragma unroll
        for (int i = 1; i < 8; ++i) {
            qv = rp4[i];
            mc = fminf(mc, fminf(fminf(qv.x, qv.y), fminf(qv.z, qv.w)));
        }
        qv = rp4[8];
        mc = fminf(mc, fminf(qv.x, fminf(qv.y, qv.z)));
        float a35 = qv.w;
        qv = rp4[9];
        float a36 = qv.x, a37 = qv.y;
        float4 r;
        r.x = fminf(fminf(a0, a1), fminf(a2, mc));
        r.y = fminf(fminf(a1, a2), fminf(mc, a35));
        r.z = fminf(fminf(a2, mc), fminf(a35, a36));
        r.w = fminf(fminf(mc, a35), fminf(a36, a37));
        *(float4*)(scr + (size_t)(tens * 4 + b) * HW_ + yg * W_ + x0) = r;
    }
}

// ---- Pass C: grid-sectioned tail.
// Blocks [0,1024): 3x3 zero-pad conv from ws A planes -> Hn, Xn.
// Blocks [1024,3072): vertical 35-tap reflect min + soft threshold -> Pn/Qn.
__global__ __launch_bounds__(256) void kTail(const float* __restrict__ wsA,
                                             const float* __restrict__ scr,
                                             const float* __restrict__ hw,
                                             const float* __restrict__ g1p,
                                             const float* __restrict__ g4p,
                                             float* __restrict__ out) {
    __shared__ float A_lds[3][4][528];  // rows y0-1..y0+2, main data at [4,516)
    __shared__ float wsh[81];
    int t = threadIdx.x;

    if (blockIdx.x < 1024) {
        // ---- conv section: block = (b, 2 output rows) ----
        int b = blockIdx.x >> 8;
        int y0b = (blockIdx.x & 255) * 2;
        if (t < 81) wsh[t] = hw[t];
        const float4* A4g = (const float4*)wsA;
        #pragma unroll
        for (int k = 0; k < 6; ++k) {
            int idx = t + k * 256;              // 0..1535
            int rc = idx >> 7;                  // 0..11
            int col4 = idx & 127;
            int c = rc >> 2, r = rc & 3;
            int yy = y0b - 1 + r;
            float4 a = make_float4(0.f, 0.f, 0.f, 0.f);
            if (yy >= 0 && yy < H_)
                a = A4g[(size_t)(b * 3 + c) * HW4_ + (size_t)yy * 128 + col4];
            *(float4*)(&A_lds[c][r][4 + col4 * 4]) = a;
        }
        if (t < 24) {                           // x-halo zeros: cells [3] and [516]
            int pair = t >> 1, side = t & 1;
            A_lds[pair >> 2][pair & 3][side ? 516 : 3] = 0.f;
        }
        __syncthreads();

        float g4 = g4p[0];
        int tl = t & 127, r_out = t >> 7;
        float cacc[3][4] = {{0.f,0.f,0.f,0.f},{0.f,0.f,0.f,0.f},{0.f,0.f,0.f,0.f}};
        #pragma unroll
        for (int i = 0; i < 3; ++i) {
            #pragma unroll
            for (int ky = 0; ky < 3; ++ky) {
                const float* Ar = &A_lds[i][r_out + ky][0];
                const float* wp0 = &wsh[0 * 27 + i * 9 + ky * 3];
                const float* wp1 = &wsh[1 * 27 + i * 9 + ky * 3];
                const float* wp2 = &wsh[2 * 27 + i * 9 + ky * 3];
                float w00 = wp0[0], w01 = wp0[1], w02 = wp0[2];
                float w10 = wp1[0], w11 = wp1[1], w12 = wp1[2];
                float w20 = wp2[0], w21 = wp2[1], w22 = wp2[2];
                #pragma unroll
                for (int j = 0; j < 4; ++j) {
                    int x = tl + 128 * j;
                    float am = Ar[3 + x], a0 = Ar[4 + x], ap = Ar[5 + x];
                    cacc[0][j] += w00 * am + w01 * a0 + w02 * ap;
                    cacc[1][j] += w10 * am + w11 * a0 + w12 * ap;
                    cacc[2][j] += w20 * am + w21 * a0 + w22 * ap;
                }
            }
        }
        int ygc = y0b + r_out;
        #pragma unroll
        for (int o = 0; o < 3; ++o) {
            #pragma unroll
            for (int j = 0; j < 4; ++j) {
                int x = tl + 128 * j;
                size_t oo = (size_t)(b * 3 + o) * HW_ + (size_t)ygc * W_ + x;
                float hn = cacc[o][j];
                float Ac = A_lds[o][r_out + 1][4 + x];
                __builtin_nontemporal_store(hn, &out[O_Hn + oo]);
                __builtin_nontemporal_store(g4 * (Ac - hn), &out[O_Xn + oo]);
            }
        }
    } else {
        // ---- vertical 35-tap reflect min + soft threshold ----
        int bid = blockIdx.x - 1024;            // 0..2047
        int tensor = bid >> 10;
        int lid = ((bid & 1023) << 8) + t;
        int b = lid >> 16, qq = lid & (HW4_ - 1);
        int y = qq >> 7, xq = (qq & 127) << 2;
        const float* R = scr + (size_t)(tensor * 4 + b) * HW_;
        float4 m = make_float4(1e30f, 1e30f, 1e30f, 1e30f);
        #pragma unroll
        for (int k = 0; k < 35; ++k) {
            int yy = y + k - 17;
            yy = yy < 0 ? -yy : (yy >= H_ ? 2 * H_ - 2 - yy : yy);
            float4 r4 = *(const float4*)(R + yy * W_ + xq);
            m.x = fminf(m.x, r4.x); m.y = fminf(m.y, r4.y);
            m.z = fminf(m.z, r4.z); m.w = fminf(m.w, r4.w);
        }
        float lam = 1.0f / g1p[0];              // lam4/g1 == lam5/g1 == 1/g1
        float4 r;
#define SOFT(m_, r_) { float s = (m_ > 0.f) ? 1.f : (m_ < 0.f ? -1.f : 0.f); \
                       r_ = s * fmaxf(fabsf(m_) - lam, 0.f); }
        SOFT(m.x, r.x) SOFT(m.y, r.y) SOFT(m.z, r.z) SOFT(m.w, r.w)
#undef SOFT
        nt_store4(r, (float4*)(out + (tensor ? O_Qn : O_Pn) + b * HW_ + y * W_ + xq));
    }
}

extern "C" void kernel_launch(void* const* d_in, const int* in_sizes, int n_in,
                              void* d_out, int out_size, void* d_ws, size_t ws_size,
                              hipStream_t stream) {
    (void)in_sizes; (void)n_in; (void)out_size; (void)ws_size;
    const float* I   = (const float*)d_in[0];
    const float* t_p = (const float*)d_in[1];
    const float* B_p = (const float*)d_in[2];
    const float* tt  = (const float*)d_in[4];
    const float* J   = (const float*)d_in[5];
    const float* G   = (const float*)d_in[6];
    const float* Hm  = (const float*)d_in[7];
    const float* u   = (const float*)d_in[10];
    const float* v   = (const float*)d_in[11];
    const float* X   = (const float*)d_in[12];
    const float* Y   = (const float*)d_in[13];
    const float* g1  = (const float*)d_in[14];
    const float* g2  = (const float*)d_in[15];
    const float* g3  = (const float*)d_in[16];
    const float* g4  = (const float*)d_in[17];
    const float* g5  = (const float*)d_in[18];
    const float* t1w = (const float*)d_in[19];
    const float* hw  = (const float*)d_in[20];
    float* out = (float*)d_out;
    float* ws  = (float*)d_ws;

    float* acc = ws + WS_ACC;
    float* wsA = ws + WS_A;
    float* scr = ws + WS_SCR;

    hipMemsetAsync(acc, 0, 64 * sizeof(float), stream);
    kRed<<<512, 256, 0, stream>>>(J, tt, B_p, I, acc);
    kMain<<<1024, 256, 0, stream>>>(I, t_p, Hm, X, J, u, v, Y, G,
                                    g1, g2, g3, g4, g5, t1w, acc, out, wsA, scr);
    kTail<<<3072, 256, 0, stream>>>(wsA, scr, hw, g1, g4, out);
}

// Round 2
// 310.726 us; speedup vs baseline: 1.0016x; 1.0016x over previous
//
#include <hip/hip_runtime.h>
#include <math.h>

// Problem geometry
#define W_ 512
#define H_ 512
#define HW_ 262144          // 512*512 = 2^18
#define HW4_ 65536          // HW/4 (float4 units)
#define CHW_ 786432         // 3*HW

// d_out offsets (floats), return order:
// (Bn, tn, Jn, G, Hn, Pn, Qn, un, vn, Xn, Yn, gamma_3)
#define O_Bn 0
#define O_tn 3145728
#define O_Jn 6291456
#define O_G  9437184
#define O_Hn 12582912
#define O_Pn 15728640
#define O_Qn 16777216
#define O_un 17825792
#define O_vn 20971520
#define O_Xn 24117248
#define O_Yn 27262976
#define O_g3 30408704

#define LAM2 0.7f
#define LAM3 0.3f

// ws layout (floats)
#define WS_ACC    0        // 64 floats, zeroed by hipMemsetAsync (60 used: [b*15+s])
#define WS_SCR    16384    // 2*4*HW floats (H-min scratch)

// native clang vector for nontemporal 16B stores (HIP float4 is a class type
// that __builtin_nontemporal_store rejects)
typedef float nfloat4 __attribute__((ext_vector_type(4)));

__device__ __forceinline__ void nt_store4(float4 v, float4* p) {
    nfloat4 nv; nv.x = v.x; nv.y = v.y; nv.z = v.z; nv.w = v.w;
    __builtin_nontemporal_store(nv, (nfloat4*)p);
}

// ---- Pass A: fused reduction over I, t, B_p, J -> 60 atomic accumulators.
// Per batch b, 15 sums: sJ[c] (3), S1[c] (3), S2[l][c] (9):
//   den = (1-t_c)^2 + lam3
//   S1[c]    = sum[ (lam3*B_p - (J_c*t_c - I_c)*(1-t_c)) / den ]
//   S2[l][c] = sum[ J_l * t_c*(1-t_c) / den ]
// Kernel boundary = barrier: kMain's prologue does the finalize per block.
__global__ __launch_bounds__(256) void kRed(const float* __restrict__ J,
                                            const float* __restrict__ tt,
                                            const float* __restrict__ B_p,
                                            const float* __restrict__ I,
                                            float* __restrict__ acc) {
    int blk = blockIdx.x;              // 0..511
    int b = blk >> 7, chunk = blk & 127;
    size_t pb = (size_t)b * (CHW_ / 4);
    size_t cb = (size_t)chunk * 512;
    const float4* J4 = (const float4*)J;
    const float4* t4 = (const float4*)tt;
    const float4* B4 = (const float4*)B_p;
    const float4* I4 = (const float4*)I;

    float aJ[3] = {0.f, 0.f, 0.f};
    float a1[3] = {0.f, 0.f, 0.f};
    float a2[9] = {0.f, 0.f, 0.f, 0.f, 0.f, 0.f, 0.f, 0.f, 0.f};

    #pragma unroll
    for (int k = 0; k < 2; ++k) {
        size_t o = cb + threadIdx.x + k * 256;
        float4 j0 = J4[pb + 0 * HW4_ + o];
        float4 j1 = J4[pb + 1 * HW4_ + o];
        float4 j2 = J4[pb + 2 * HW4_ + o];
        #pragma unroll
        for (int c = 0; c < 3; ++c) {
            float4 tv = t4[pb + (size_t)c * HW4_ + o];
            float4 bp = B4[pb + (size_t)c * HW4_ + o];
            float4 iv = I4[pb + (size_t)c * HW4_ + o];
            float4 jc = (c == 0) ? j0 : (c == 1 ? j1 : j2);
#define REDC(m) { \
            float omt = 1.f - tv.m; \
            float r = 1.f / (omt * omt + LAM3); \
            float g = tv.m * omt * r; \
            aJ[c] += jc.m; \
            a1[c] += (LAM3 * bp.m - (jc.m * tv.m - iv.m) * omt) * r; \
            a2[0 * 3 + c] += j0.m * g; \
            a2[1 * 3 + c] += j1.m * g; \
            a2[2 * 3 + c] += j2.m * g; }
            REDC(x) REDC(y) REDC(z) REDC(w)
#undef REDC
        }
    }

    float vals[15];
    #pragma unroll
    for (int c = 0; c < 3; ++c) { vals[c] = aJ[c]; vals[3 + c] = a1[c]; }
    #pragma unroll
    for (int s = 0; s < 9; ++s) vals[6 + s] = a2[s];

    __shared__ float lds[4][15];
    int lane = threadIdx.x & 63, w = threadIdx.x >> 6;
    #pragma unroll
    for (int s = 0; s < 15; ++s) {
        float v = vals[s];
        #pragma unroll
        for (int off = 32; off; off >>= 1) v += __shfl_down(v, off, 64);
        if (lane == 0) lds[w][s] = v;
    }
    __syncthreads();
    if (threadIdx.x < 15) {
        int s = threadIdx.x;
        atomicAdd(&acc[b * 15 + s],
                  (lds[0][s] + lds[1][s]) + (lds[2][s] + lds[3][s]));
    }
}

// ---- Pass B: fused elementwise + finalize-prologue + horizontal 35-tap
// reflect-min + 3x3 zero-pad conv (halo-row t1 recompute). Block = 2 rows.
// (Round-0 measured-best structure; halo reads are L2-hits from neighbor
// blocks, so in-kernel conv beats the A-plane ws round-trip variant.)
__global__ __launch_bounds__(256) void kMain(
    const float* __restrict__ I, const float* __restrict__ t_p,
    const float* __restrict__ Hm, const float* __restrict__ Xm,
    const float* __restrict__ J, const float* __restrict__ u,
    const float* __restrict__ v, const float* __restrict__ Y,
    const float* __restrict__ G,
    const float* __restrict__ g1p, const float* __restrict__ g2p,
    const float* __restrict__ g3p, const float* __restrict__ g4p,
    const float* __restrict__ g5p, const float* __restrict__ t1w,
    const float* __restrict__ hw, const float* __restrict__ acc,
    float* __restrict__ out, float* __restrict__ scr)
{
    __shared__ float pad[2][2][560];    // h-min rows, main data at [17,529)
    __shared__ float A_lds[3][4][528];  // conv input rows y0-1..y0+2, main [4,516)
    __shared__ float wsh[81];
    __shared__ float sAlpha[3], sBnS[3];
    __shared__ int sI2;

    int t = threadIdx.x;
    int b = blockIdx.x >> 8;            // 4 batches x 256 row-pairs
    int y0b = (blockIdx.x & 255) * 2;
    float g1 = g1p[0], g2 = g2p[0], g3 = g3p[0], g4 = g4p[0], g5 = g5p[0];
    float ig4 = 1.f / g4;

    // ---- prologue: per-block finalize (argsort, alpha, BnS) ----
    if (t == 0) {
        const float invHW = 1.0f / (float)HW_;
        float tot[15];
        #pragma unroll
        for (int s = 0; s < 15; ++s) tot[s] = acc[b * 15 + s];
        float m[3] = {tot[0] * invHW, tot[1] * invHW, tot[2] * invHW};
        int r[3];
        #pragma unroll
        for (int i = 0; i < 3; ++i) {
            int ri = 0;
            #pragma unroll
            for (int j = 0; j < 3; ++j)
                if (j != i && (m[j] < m[i] || (m[j] == m[i] && j < i))) ri++;
            r[i] = ri;   // ascending stable rank
        }
        int idx[3]; float ms[3];
        #pragma unroll
        for (int i = 0; i < 3; ++i) { idx[r[i]] = i; ms[r[i]] = m[i]; }
        sI2 = idx[2];
        float a[3] = {0.f, 0.f, 0.f};
        a[idx[1]] = ms[2] - ms[1];
        a[idx[0]] = ms[2] - ms[0];
        #pragma unroll
        for (int c = 0; c < 3; ++c) {
            sAlpha[c] = a[c];
            sBnS[c] = (tot[3 + c] - a[c] * tot[6 + idx[2] * 3 + c]) * invHW;
        }
        if (blockIdx.x == 0) out[O_g3] = g3;
    }
    if (t < 81) wsh[t] = hw[t];
    __syncthreads();

    int rrow = t >> 7;                  // row within block: 0..1
    int xq = t & 127;                   // float4 col
    int x0 = xq * 4;
    size_t pb = (size_t)b * (CHW_ / 4);
    size_t q = (size_t)(y0b + rrow) * 128 + xq;   // float4 offset in plane
    float wc[3] = {t1w[0], t1w[1], t1w[2]};
    int i2 = sI2;
    const float4* I4p = (const float4*)I;
    const float4* tp4p = (const float4*)t_p;
    const float4* H4p = (const float4*)Hm;
    const float4* X4p = (const float4*)Xm;
    const float4* J4p = (const float4*)J;
    const float4* u4p = (const float4*)u;
    const float4* v4p = (const float4*)v;
    const float4* Y4p = (const float4*)Y;
    const float4* G4p = (const float4*)G;
    float4* o4 = (float4*)out;

    // ---- phase 1: main 2 rows, full elementwise ----
    float4 j0 = J4p[pb + 0 * HW4_ + q];
    float4 j1 = J4p[pb + 1 * HW4_ + q];
    float4 j2 = J4p[pb + 2 * HW4_ + q];
    float4 Jl = (i2 == 0) ? j0 : (i2 == 1 ? j1 : j2);   // wave-uniform select
    float4 t1 = make_float4(0.f, 0.f, 0.f, 0.f);
    float4 Isv[3], Xsv[3]; float Bsv[3];
    const float den2 = LAM2 + g4;
    #pragma unroll
    for (int c = 0; c < 3; ++c) {
        size_t o = pb + (size_t)c * HW4_ + q;
        float4 I4 = I4p[o], tp4 = tp4p[o], H4 = H4p[o], X4 = X4p[o];
        float4 Jv = (c == 0) ? j0 : (c == 1 ? j1 : j2);
        float al = sAlpha[c], Bnv = sBnS[c];
        float wcc = wc[c];
#define STEP1(m) { \
        float d_ = (Jv.m + al * Jl.m) - Bnv; \
        float tnr_ = (LAM2 * tp4.m + g4 * H4.m - (Bnv - I4.m) * d_ - X4.m) / (d_ * d_ + den2); \
        t1.m += wcc * tnr_; }
        STEP1(x) STEP1(y) STEP1(z) STEP1(w)
#undef STEP1
        Isv[c] = I4; Xsv[c] = X4; Bsv[c] = Bnv;
    }
    float g345 = g3 + g4 + g5;
    float4 invDen;
    invDen.x = 1.f / (t1.x * t1.x + g345);
    invDen.y = 1.f / (t1.y * t1.y + g345);
    invDen.z = 1.f / (t1.z * t1.z + g345);
    invDen.w = 1.f / (t1.w * t1.w + g345);
    float invDu = 1.f / (g1 + g4), invDv = 1.f / (g2 + g5);
    float4 cu = make_float4(1e30f, 1e30f, 1e30f, 1e30f);
    float4 cv = cu;
    #pragma unroll
    for (int c = 0; c < 3; ++c) {
        size_t o = pb + (size_t)c * HW4_ + q;
        float4 u4 = u4p[o], v4 = v4p[o], Y4 = Y4p[o], G4 = G4p[o];
        float Bnv = Bsv[c];
        float4 Jn4, un4, vn4, Yn4;
#define STEP2(m) { \
        float Jn_ = (t1.m * (Isv[c].m - Bnv * (1.f - t1.m)) + g3 * G4.m + g4 * u4.m \
                     - g5 * v4.m - Y4.m + g5) * invDen.m; \
        float un_ = (g1 * u4.m + g4 * Jn_) * invDu; \
        float vn_ = (g2 * v4.m - g5 * Jn_ + g5) * invDv; \
        Jn4.m = Jn_; un4.m = un_; vn4.m = vn_; \
        Yn4.m = Y4.m + g3 * (Jn_ - G4.m); \
        cu.m = fminf(cu.m, un_); cv.m = fminf(cv.m, vn_); }
        STEP2(x) STEP2(y) STEP2(z) STEP2(w)
#undef STEP2
        nt_store4(make_float4(Bnv, Bnv, Bnv, Bnv), &o4[O_Bn / 4 + o]);
        nt_store4(t1,  &o4[O_tn / 4 + o]);
        nt_store4(Jn4, &o4[O_Jn / 4 + o]);
        nt_store4(G4,  &o4[O_G  / 4 + o]);
        nt_store4(un4, &o4[O_un / 4 + o]);
        nt_store4(vn4, &o4[O_vn / 4 + o]);
        nt_store4(Yn4, &o4[O_Yn / 4 + o]);
        // conv input A center rows
        float4 A4;
        A4.x = t1.x + Xsv[c].x * ig4; A4.y = t1.y + Xsv[c].y * ig4;
        A4.z = t1.z + Xsv[c].z * ig4; A4.w = t1.w + Xsv[c].w * ig4;
        *(float4*)(&A_lds[c][1 + rrow][4 + x0]) = A4;
    }
    // h-min staging
    pad[0][rrow][17 + x0 + 0] = cu.x;
    pad[0][rrow][17 + x0 + 1] = cu.y;
    pad[0][rrow][17 + x0 + 2] = cu.z;
    pad[0][rrow][17 + x0 + 3] = cu.w;
    pad[1][rrow][17 + x0 + 0] = cv.x;
    pad[1][rrow][17 + x0 + 1] = cv.y;
    pad[1][rrow][17 + x0 + 2] = cv.z;
    pad[1][rrow][17 + x0 + 3] = cv.w;

    // ---- phase 2: halo rows (y0-1, y0+2) — t1 only, build A rows 0/3 ----
    {
        int hr = (rrow == 0) ? (y0b - 1) : (y0b + 2);
        int ar = (rrow == 0) ? 0 : 3;
        if (hr >= 0 && hr < H_) {
            size_t hq = (size_t)hr * 128 + xq;
            float4 h0 = J4p[pb + 0 * HW4_ + hq];
            float4 h1 = J4p[pb + 1 * HW4_ + hq];
            float4 h2 = J4p[pb + 2 * HW4_ + hq];
            float4 Jlh = (i2 == 0) ? h0 : (i2 == 1 ? h1 : h2);
            float4 t1h = make_float4(0.f, 0.f, 0.f, 0.f);
            float4 Xh[3];
            #pragma unroll
            for (int c = 0; c < 3; ++c) {
                size_t o = pb + (size_t)c * HW4_ + hq;
                float4 I4 = I4p[o], tp4 = tp4p[o], H4 = H4p[o], X4 = X4p[o];
                float4 Jv = (c == 0) ? h0 : (c == 1 ? h1 : h2);
                float al = sAlpha[c], Bnv = sBnS[c];
                float wcc = wc[c];
#define STEP1H(m) { \
                float d_ = (Jv.m + al * Jlh.m) - Bnv; \
                float tnr_ = (LAM2 * tp4.m + g4 * H4.m - (Bnv - I4.m) * d_ - X4.m) / (d_ * d_ + den2); \
                t1h.m += wcc * tnr_; }
                STEP1H(x) STEP1H(y) STEP1H(z) STEP1H(w)
#undef STEP1H
                Xh[c] = X4;
            }
            #pragma unroll
            for (int c = 0; c < 3; ++c) {
                float4 A4;
                A4.x = t1h.x + Xh[c].x * ig4; A4.y = t1h.y + Xh[c].y * ig4;
                A4.z = t1h.z + Xh[c].z * ig4; A4.w = t1h.w + Xh[c].w * ig4;
                *(float4*)(&A_lds[c][ar][4 + x0]) = A4;
            }
        } else {
            float4 z = make_float4(0.f, 0.f, 0.f, 0.f);
            #pragma unroll
            for (int c = 0; c < 3; ++c)
                *(float4*)(&A_lds[c][ar][4 + x0]) = z;
        }
    }
    if (t < 24) {                        // x-halo zeros: cells [3] and [516]
        int pair = t >> 1, side = t & 1;
        A_lds[pair >> 2][pair & 3][side ? 516 : 3] = 0.f;
    }
    __syncthreads();

    // ---- pad reflect edge fill ----
    if (t < 136) {                      // 4 rows x 34 cells
        int which = t / 34, e = t % 34;
        int tens = which >> 1, rw = which & 1;
        int j   = (e < 17) ? e : (529 + (e - 17));
        int src = (e < 17) ? (34 - j) : (1056 - j);
        pad[tens][rw][j] = pad[tens][rw][src];
    }
    __syncthreads();

    // ---- phase 3: horizontal 35-tap reflect min -> scr ----
    int yg = y0b + rrow;
    #pragma unroll
    for (int tens = 0; tens < 2; ++tens) {
        const float* rowp = &pad[tens][rrow][0];
        const float4* rp4 = (const float4*)(rowp + x0);   // 16B-aligned
        float4 qv = rp4[0];
        float a0 = qv.x, a1 = qv.y, a2 = qv.z;
        float mc = qv.w;
        #pragma unroll
        for (int i = 1; i < 8; ++i) {
            qv = rp4[i];
            mc = fminf(mc, fminf(fminf(qv.x, qv.y), fminf(qv.z, qv.w)));
        }
        qv = rp4[8];
        mc = fminf(mc, fminf(qv.x, fminf(qv.y, qv.z)));
        float a35 = qv.w;
        qv = rp4[9];
        float a36 = qv.x, a37 = qv.y;
        float4 r;
        r.x = fminf(fminf(a0, a1), fminf(a2, mc));
        r.y = fminf(fminf(a1, a2), fminf(mc, a35));
        r.z = fminf(fminf(a2, mc), fminf(a35, a36));
        r.w = fminf(fminf(mc, a35), fminf(a36, a37));
        *(float4*)(scr + (size_t)(tens * 4 + b) * HW_ + yg * W_ + x0) = r;
    }

    // ---- phase 4: 3x3 zero-pad conv from A_lds -> Hn, Xn ----
    {
        int tl = t & 127, r_out = t >> 7;
        float cacc[3][4] = {{0.f,0.f,0.f,0.f},{0.f,0.f,0.f,0.f},{0.f,0.f,0.f,0.f}};
        #pragma unroll
        for (int i = 0; i < 3; ++i) {
            #pragma unroll
            for (int ky = 0; ky < 3; ++ky) {
                const float* Ar = &A_lds[i][r_out + ky][0];
                const float* wp0 = &wsh[0 * 27 + i * 9 + ky * 3];
                const float* wp1 = &wsh[1 * 27 + i * 9 + ky * 3];
                const float* wp2 = &wsh[2 * 27 + i * 9 + ky * 3];
                float w00 = wp0[0], w01 = wp0[1], w02 = wp0[2];
                float w10 = wp1[0], w11 = wp1[1], w12 = wp1[2];
                float w20 = wp2[0], w21 = wp2[1], w22 = wp2[2];
                #pragma unroll
                for (int j = 0; j < 4; ++j) {
                    int x = tl + 128 * j;
                    float am = Ar[3 + x], a0 = Ar[4 + x], ap = Ar[5 + x];
                    cacc[0][j] += w00 * am + w01 * a0 + w02 * ap;
                    cacc[1][j] += w10 * am + w11 * a0 + w12 * ap;
                    cacc[2][j] += w20 * am + w21 * a0 + w22 * ap;
                }
            }
        }
        int ygc = y0b + r_out;
        #pragma unroll
        for (int o = 0; o < 3; ++o) {
            #pragma unroll
            for (int j = 0; j < 4; ++j) {
                int x = tl + 128 * j;
                size_t oo = (size_t)(b * 3 + o) * HW_ + (size_t)ygc * W_ + x;
                float hn = cacc[o][j];
                float Ac = A_lds[o][r_out + 1][4 + x];
                __builtin_nontemporal_store(hn, &out[O_Hn + oo]);
                __builtin_nontemporal_store(g4 * (Ac - hn), &out[O_Xn + oo]);
            }
        }
    }
}

// ---- Pass C: vertical 35-tap reflect min + soft threshold -> Pn/Qn ----
__global__ __launch_bounds__(256) void kVMin(const float* __restrict__ scr,
                                             const float* __restrict__ g1p,
                                             float* __restrict__ out) {
    int t = threadIdx.x;
    int tensor = blockIdx.x >> 10;
    int lid = ((blockIdx.x & 1023) << 8) + t;
    int b = lid >> 16, qq = lid & (HW4_ - 1);
    int y = qq >> 7, xq = (qq & 127) << 2;
    const float* R = scr + (size_t)(tensor * 4 + b) * HW_;
    float4 m = make_float4(1e30f, 1e30f, 1e30f, 1e30f);
    #pragma unroll
    for (int k = 0; k < 35; ++k) {
        int yy = y + k - 17;
        yy = yy < 0 ? -yy : (yy >= H_ ? 2 * H_ - 2 - yy : yy);
        float4 r4 = *(const float4*)(R + yy * W_ + xq);
        m.x = fminf(m.x, r4.x); m.y = fminf(m.y, r4.y);
        m.z = fminf(m.z, r4.z); m.w = fminf(m.w, r4.w);
    }
    float lam = 1.0f / g1p[0];            // lam4/g1 == lam5/g1 == 1/g1
    float4 r;
#define SOFT(m_, r_) { float s = (m_ > 0.f) ? 1.f : (m_ < 0.f ? -1.f : 0.f); \
                       r_ = s * fmaxf(fabsf(m_) - lam, 0.f); }
    SOFT(m.x, r.x) SOFT(m.y, r.y) SOFT(m.z, r.z) SOFT(m.w, r.w)
#undef SOFT
    nt_store4(r, (float4*)(out + (tensor ? O_Qn : O_Pn) + b * HW_ + y * W_ + xq));
}

extern "C" void kernel_launch(void* const* d_in, const int* in_sizes, int n_in,
                              void* d_out, int out_size, void* d_ws, size_t ws_size,
                              hipStream_t stream) {
    (void)in_sizes; (void)n_in; (void)out_size; (void)ws_size;
    const float* I   = (const float*)d_in[0];
    const float* t_p = (const float*)d_in[1];
    const float* B_p = (const float*)d_in[2];
    const float* tt  = (const float*)d_in[4];
    const float* J   = (const float*)d_in[5];
    const float* G   = (const float*)d_in[6];
    const float* Hm  = (const float*)d_in[7];
    const float* u   = (const float*)d_in[10];
    const float* v   = (const float*)d_in[11];
    const float* X   = (const float*)d_in[12];
    const float* Y   = (const float*)d_in[13];
    const float* g1  = (const float*)d_in[14];
    const float* g2  = (const float*)d_in[15];
    const float* g3  = (const float*)d_in[16];
    const float* g4  = (const float*)d_in[17];
    const float* g5  = (const float*)d_in[18];
    const float* t1w = (const float*)d_in[19];
    const float* hw  = (const float*)d_in[20];
    float* out = (float*)d_out;
    float* ws  = (float*)d_ws;

    float* acc = ws + WS_ACC;
    float* scr = ws + WS_SCR;

    hipMemsetAsync(acc, 0, 64 * sizeof(float), stream);
    kRed<<<512, 256, 0, stream>>>(J, tt, B_p, I, acc);
    kMain<<<1024, 256, 0, stream>>>(I, t_p, Hm, X, J, u, v, Y, G,
                                    g1, g2, g3, g4, g5, t1w, hw, acc, out, scr);
    kVMin<<<2048, 256, 0, stream>>>(scr, g1, out);
}